// Round 2
// baseline (969.738 us; speedup 1.0000x reference)
//
#include <hip/hip_runtime.h>
#include <stdint.h>

typedef __bf16 bf16;
typedef __attribute__((ext_vector_type(8))) __bf16 bf16x8;
typedef __attribute__((ext_vector_type(4))) float f32x4;

#define N_TOK 8192
#define C_DIM 1024
#define I_DIM 1408
#define NE 8
#define NEA 9

// ---- workspace byte offsets (identical footprint to R1, 162 MiB) ----
#define CNT_OFF   0
#define OFFS_OFF  64
#define BTOK_OFF  128
#define BP_OFF    (BTOK_OFF + NE * N_TOK * 4)
#define ROUTER_END (BP_OFF + NE * N_TOK * 4)
#define XB_OFF    (1u << 20)
#define WB1_OFF   (18u << 20)
#define WB2_OFF   (43u << 20)
#define WB3_OFF   (68u << 20)
#define H_OFF     (93u << 20)
#define H_ROWS    25600

__device__ __forceinline__ void gload16(const void* g, void* l) {
  __builtin_amdgcn_global_load_lds(
      (const __attribute__((address_space(1))) void*)g,
      (__attribute__((address_space(3))) void*)l, 16, 0, 0);
}

__device__ __forceinline__ void vmwait_sel(int n) {
  if (n == 0) asm volatile("s_waitcnt vmcnt(0)" ::: "memory");
  else if (n == 4) asm volatile("s_waitcnt vmcnt(4)" ::: "memory");
  else if (n == 6) asm volatile("s_waitcnt vmcnt(6)" ::: "memory");
}

#define SCHED() __builtin_amdgcn_sched_barrier(0)
#define BARRIER() __builtin_amdgcn_s_barrier()

// ---------------- conversion fp32 -> bf16 ----------------
__global__ __launch_bounds__(256) void convert_kernel(
    const float* __restrict__ src, bf16* __restrict__ dst, int n8) {
  int i = blockIdx.x * 256 + threadIdx.x;
  if (i >= n8) return;
  const float* s = src + (size_t)i * 8;
  float4 a = *(const float4*)(s);
  float4 b = *(const float4*)(s + 4);
  bf16x8 v;
  v[0] = (bf16)a.x; v[1] = (bf16)a.y; v[2] = (bf16)a.z; v[3] = (bf16)a.w;
  v[4] = (bf16)b.x; v[5] = (bf16)b.y; v[6] = (bf16)b.z; v[7] = (bf16)b.w;
  *(bf16x8*)(dst + (size_t)i * 8) = v;
}

// ---------------- router ----------------
__global__ __launch_bounds__(256) void router_kernel(
    const float* __restrict__ x, const float* __restrict__ Wg,
    int* __restrict__ cnt, int* __restrict__ btok, float* __restrict__ bp) {
  __shared__ __align__(16) float wg[NE * C_DIM];
  int t = threadIdx.x;
#pragma unroll
  for (int j = 0; j < 8; ++j) {
    int idx = (t + 256 * j) * 4;
    *(float4*)&wg[idx] = *(const float4*)&Wg[idx];
  }
  __syncthreads();
  int wid = t >> 6, lane = t & 63;
  int tok = blockIdx.x * 4 + wid;
  const float* xr = x + (size_t)tok * C_DIM;
  float acc[NE];
#pragma unroll
  for (int e = 0; e < NE; ++e) acc[e] = 0.f;
#pragma unroll
  for (int j = 0; j < 4; ++j) {
    int c4 = (lane + 64 * j) * 4;
    float4 xv = *(const float4*)&xr[c4];
#pragma unroll
    for (int e = 0; e < NE; ++e) {
      float4 wv = *(const float4*)&wg[e * C_DIM + c4];
      acc[e] += xv.x * wv.x + xv.y * wv.y + xv.z * wv.z + xv.w * wv.w;
    }
  }
  for (int o = 32; o >= 1; o >>= 1)
#pragma unroll
    for (int e = 0; e < NE; ++e) acc[e] += __shfl_xor(acc[e], o, 64);
  if (lane == 0) {
    float m = acc[0];
#pragma unroll
    for (int e = 1; e < NE; ++e) m = fmaxf(m, acc[e]);
    float p[NE], s = 0.f;
#pragma unroll
    for (int e = 0; e < NE; ++e) { p[e] = __expf(acc[e] - m); s += p[e]; }
    float inv = 1.f / s;
#pragma unroll
    for (int e = 0; e < NE; ++e) p[e] *= inv;
    int e0 = 0; float p0 = p[0];
#pragma unroll
    for (int e = 1; e < NE; ++e) if (p[e] > p0) { p0 = p[e]; e0 = e; }
    int e1 = -1; float p1 = -1.f;
#pragma unroll
    for (int e = 0; e < NE; ++e) {
      if (e == e0) continue;
      if (p[e] > p1) { p1 = p[e]; e1 = e; }
    }
    int pos0 = atomicAdd(&cnt[e0], 1);
    btok[e0 * N_TOK + pos0] = tok; bp[e0 * N_TOK + pos0] = p0;
    int pos1 = atomicAdd(&cnt[e1], 1);
    btok[e1 * N_TOK + pos1] = tok; bp[e1 * N_TOK + pos1] = p1;
  }
}

__global__ void offsets_kernel(const int* __restrict__ cnt, int* __restrict__ offs) {
  if (threadIdx.x == 0) {
    int a = 0;
    for (int e = 0; e < NE; ++e) { offs[e] = a; a += (cnt[e] + 127) & ~127; }
    offs[NE] = a;
  }
}

// ================= stage1: 8-phase, BM=256 BN=128 dual-B (G,U) =================
// LDS buffer (64KB): [A0 16K | A1 16K | B1 16K | B2 16K], 2 buffers.
// A unit: 256 rows x 32k (row stride 64B, seg swizzle p = seg ^ ((row>>1)&3))
// B unit: 128 rows x 64k (row stride 128B, sseg swizzle p = sseg ^ (row&7))
// Phases per K-tile: (s0,G)(s0,U)(s1,G)(s1,U); A-frags register-held across G/U.
// vmcnt(4) at ph4/ph8 (proven: ph4 retires through B2(t1)@ph2; ph8 through B2(t0+2)@ph6)

#define PH1(BASE, S, W, ACC, READA, STAGE, VMN)                                \
  {                                                                            \
    if (READA) {                                                               \
      _Pragma("unroll") for (int mf = 0; mf < 8; ++mf)                         \
          av[mf] = *(const bf16x8*)((BASE) + (S)*16384 + aoff[mf]);            \
    }                                                                          \
    _Pragma("unroll") for (int nf = 0; nf < 2; ++nf)                           \
        bv[nf] = *(const bf16x8*)((BASE) + (W)*16384 + boff[S][nf]);           \
    STAGE;                                                                     \
    SCHED(); BARRIER(); SCHED();                                               \
    asm volatile("s_waitcnt lgkmcnt(0)" ::: "memory");                         \
    SCHED();                                                                   \
    __builtin_amdgcn_s_setprio(1);                                             \
    _Pragma("unroll") for (int mf = 0; mf < 8; ++mf)                           \
        _Pragma("unroll") for (int nf = 0; nf < 2; ++nf)                       \
            ACC[mf][nf] = __builtin_amdgcn_mfma_f32_16x16x32_bf16(             \
                av[mf], bv[nf], ACC[mf][nf], 0, 0, 0);                         \
    __builtin_amdgcn_s_setprio(0);                                             \
    SCHED();                                                                   \
    vmwait_sel(VMN);                                                           \
    BARRIER(); SCHED();                                                        \
  }

__global__ __launch_bounds__(512, 2) void stage1_kernel(
    const bf16* __restrict__ xb, const bf16* __restrict__ wb1,
    const bf16* __restrict__ wb2, const int* __restrict__ cnt,
    const int* __restrict__ offs, const int* __restrict__ btok,
    bf16* __restrict__ H) {
  int e = blockIdx.z;
  int padded = (e == NE) ? N_TOK : ((cnt[e] + 127) & ~127);
  int row0 = blockIdx.x * 256;
  if (row0 >= padded) return;
  int i0 = blockIdx.y * 128;
  int slotbase = (e == NE) ? 0 : (N_TOK + offs[e]);

  __shared__ __align__(16) char smem[131072];
  const int t = threadIdx.x;
  const int lane = t & 63, wid = t >> 6;
  const int wr = wid >> 2, wc = wid & 3;
  const int l15 = lane & 15, l4 = lane >> 4;

  // staging setup
  const int arow = t >> 2, p4 = t & 3;
  const int gsegA = p4 ^ ((arow >> 1) & 3);
  int r0i = row0 + arow, r1i = row0 + arow + 128;
  int tok0, tok1;
  if (e == NE) { tok0 = r0i; tok1 = r1i; }
  else {
    int i0x = e * N_TOK + (r0i < N_TOK ? r0i : N_TOK - 1);
    int i1x = e * N_TOK + (r1i < N_TOK ? r1i : N_TOK - 1);
    tok0 = btok[i0x] & (N_TOK - 1);
    tok1 = btok[i1x] & (N_TOK - 1);
  }
  const bf16* asrc0 = xb + (size_t)tok0 * C_DIM + gsegA * 8;
  const bf16* asrc1 = xb + (size_t)tok1 * C_DIM + gsegA * 8;
  const int brow = t >> 3, p8 = t & 7;
  const int gs8 = p8 ^ (brow & 7);
  const bf16* b1s = wb1 + ((size_t)e * I_DIM + i0 + brow) * C_DIM + gs8 * 8;
  const bf16* b2s = wb2 + ((size_t)e * I_DIM + i0 + brow) * C_DIM + gs8 * 8;
  const int lo0 = t * 16, lo1 = (t + 512) * 16;

  auto stA = [&](int buf, int s, int kc) {
    char* d = smem + buf * 65536 + s * 16384;
    gload16(asrc0 + kc, d + lo0);
    gload16(asrc1 + kc, d + lo1);
  };
  auto stB = [&](int buf, int w, int kc) {
    char* d = smem + buf * 65536 + 32768 + w * 16384;
    const bf16* s = (w ? b2s : b1s) + kc;
    gload16(s, d + lo0);
    gload16(s + 64 * C_DIM, d + lo1);
  };

  // fragment LDS offsets
  int aoff[8], boff[2][2];
#pragma unroll
  for (int mf = 0; mf < 8; ++mf) {
    int row = wr * 128 + mf * 16 + l15;
    aoff[mf] = row * 64 + ((l4 ^ ((row >> 1) & 3)) * 16);
  }
#pragma unroll
  for (int s = 0; s < 2; ++s)
#pragma unroll
    for (int nf = 0; nf < 2; ++nf) {
      int row = wc * 32 + nf * 16 + l15;
      boff[s][nf] = 32768 + row * 128 + ((((s << 2) + l4) ^ (row & 7)) * 16);
    }

  f32x4 accG[8][2], accU[8][2];
  f32x4 zero = {0.f, 0.f, 0.f, 0.f};
#pragma unroll
  for (int mf = 0; mf < 8; ++mf)
#pragma unroll
    for (int nf = 0; nf < 2; ++nf) { accG[mf][nf] = zero; accU[mf][nf] = zero; }
  bf16x8 av[8], bv[2];

  // prologue: buf0 <- tile0 {A0,A1,B1,B2}; buf1 <- tile1 {A0,A1}
  stA(0, 0, 0); stA(0, 1, 32); stB(0, 0, 0); stB(0, 1, 0);
  stA(1, 0, 64); stA(1, 1, 96);
  SCHED();
  asm volatile("s_waitcnt vmcnt(4)" ::: "memory");
  BARRIER(); SCHED();

  char* b0 = smem;
  char* b1m = smem + 65536;
  for (int it = 0; it < 8; ++it) {
    const int t1k = (2 * it + 1) * 64;
    const int k2 = ((2 * it + 2) & 15) * 64;
    const int k3 = ((2 * it + 3) & 15) * 64;
    // ph1: buf0 (s0,G); stage B1(buf1,t1)
    PH1(b0, 0, 0, accG, 1, { stB(1, 0, t1k); }, 99);
    // ph2: buf0 (s0,U); stage B2(buf1,t1) THEN A0(buf0,t0+2)
    PH1(b0, 0, 1, accU, 0, { stB(1, 1, t1k); stA(0, 0, k2); }, 99);
    // ph3: buf0 (s1,G)
    PH1(b0, 1, 0, accG, 1, {}, 99);
    // ph4: buf0 (s1,U); stage B1(buf0,t0+2); vmcnt(4)
    PH1(b0, 1, 1, accU, 0, { stB(0, 0, k2); }, 4);
    // ph5: buf1 (s0,G); stage A1(buf0,t0+2)
    PH1(b1m, 0, 0, accG, 1, { stA(0, 1, k2 + 32); }, 99);
    // ph6: buf1 (s0,U); stage B2(buf0,t0+2)
    PH1(b1m, 0, 1, accU, 0, { stB(0, 1, k2); }, 99);
    // ph7: buf1 (s1,G); stage A0(buf1,t1+2)
    PH1(b1m, 1, 0, accG, 1, { stA(1, 0, k3); }, 99);
    // ph8: buf1 (s1,U); stage A1(buf1,t1+2); vmcnt(4)
    PH1(b1m, 1, 1, accU, 0, { stA(1, 1, k3 + 32); }, 4);
  }
  asm volatile("s_waitcnt vmcnt(0)" ::: "memory");

  // epilogue: SwiGLU + guarded store
#pragma unroll
  for (int mf = 0; mf < 8; ++mf)
#pragma unroll
    for (int r = 0; r < 4; ++r) {
      int rr = row0 + wr * 128 + mf * 16 + l4 * 4 + r;
      bool ok = rr < padded;
#pragma unroll
      for (int nf = 0; nf < 2; ++nf) {
        float g = accG[mf][nf][r], u = accU[mf][nf][r];
        float h = (g / (1.f + __expf(-g))) * u;
        int col = i0 + wc * 32 + nf * 16 + l15;
        if (ok) H[(size_t)(slotbase + rr) * I_DIM + col] = (bf16)h;
      }
    }
}

// ================= stage2: 8-phase, 256x256, K=1408 =================
// LDS buffer: [A0|A1|B0|B1] 16KB each; all units 256 rows x 32k (64B rows).
// Phases: (s,h) h = M-frag half; B-frags register-held across h.
// vmcnt(6) at ph4/ph8 (proven for this unit ordering).

#define PH2(BASE, S, H_, STAGE, VMN)                                           \
  {                                                                            \
    if ((H_) == 0) {                                                           \
      _Pragma("unroll") for (int nf = 0; nf < 4; ++nf)                         \
          bv[nf] = *(const bf16x8*)((BASE) + (S)*16384 + boff[nf]);            \
    }                                                                          \
    _Pragma("unroll") for (int q = 0; q < 4; ++q)                              \
        av[q] = *(const bf16x8*)((BASE) + (S)*16384 + aoff[(H_)*4 + q]);       \
    STAGE;                                                                     \
    SCHED(); BARRIER(); SCHED();                                               \
    asm volatile("s_waitcnt lgkmcnt(0)" ::: "memory");                         \
    SCHED();                                                                   \
    __builtin_amdgcn_s_setprio(1);                                             \
    _Pragma("unroll") for (int q = 0; q < 4; ++q)                              \
        _Pragma("unroll") for (int nf = 0; nf < 4; ++nf)                       \
            acc[(H_)*4 + q][nf] = __builtin_amdgcn_mfma_f32_16x16x32_bf16(     \
                av[q], bv[nf], acc[(H_)*4 + q][nf], 0, 0, 0);                  \
    __builtin_amdgcn_s_setprio(0);                                             \
    SCHED();                                                                   \
    vmwait_sel(VMN);                                                           \
    BARRIER(); SCHED();                                                        \
  }

template <int ATOMIC>
__global__ __launch_bounds__(512, 2) void stage2_kernel(
    const bf16* __restrict__ H, const bf16* __restrict__ wb3,
    const int* __restrict__ cnt, const int* __restrict__ offs,
    const int* __restrict__ btok, const float* __restrict__ bp,
    float* __restrict__ y) {
  int e = ATOMIC ? blockIdx.z : NE;
  int padded = ATOMIC ? ((cnt[e] + 127) & ~127) : N_TOK;
  int row0 = blockIdx.x * 256;
  if (row0 >= padded) return;
  int c0 = blockIdx.y * 256;
  int slotbase = ATOMIC ? (N_TOK + offs[e]) : 0;

  __shared__ __align__(16) char smem[131072];
  const int t = threadIdx.x;
  const int lane = t & 63, wid = t >> 6;
  const int wr = wid >> 2, wc = wid & 3;
  const int l15 = lane & 15, l4 = lane >> 4;

  const int arow = t >> 2, p4 = t & 3;
  const int gseg = p4 ^ ((arow >> 1) & 3);
  int sr0 = slotbase + row0 + arow; if (sr0 > H_ROWS - 1) sr0 = H_ROWS - 1;
  int sr1 = slotbase + row0 + arow + 128; if (sr1 > H_ROWS - 1) sr1 = H_ROWS - 1;
  const bf16* asrc0 = H + (size_t)sr0 * I_DIM + gseg * 8;
  const bf16* asrc1 = H + (size_t)sr1 * I_DIM + gseg * 8;
  const bf16* bsrc0 = wb3 + ((size_t)e * C_DIM + c0 + arow) * I_DIM + gseg * 8;
  const bf16* bsrc1 = bsrc0 + (size_t)128 * I_DIM;
  const int lo0 = t * 16, lo1 = (t + 512) * 16;

  auto stA = [&](int buf, int s, int kc) {
    char* d = smem + buf * 65536 + s * 16384;
    gload16(asrc0 + kc, d + lo0);
    gload16(asrc1 + kc, d + lo1);
  };
  auto stB = [&](int buf, int s, int kc) {
    char* d = smem + buf * 65536 + 32768 + s * 16384;
    gload16(bsrc0 + kc, d + lo0);
    gload16(bsrc1 + kc, d + lo1);
  };

  int aoff[8], boff[4];
#pragma unroll
  for (int mf = 0; mf < 8; ++mf) {
    int row = wr * 128 + mf * 16 + l15;
    aoff[mf] = row * 64 + ((l4 ^ ((row >> 1) & 3)) * 16);
  }
#pragma unroll
  for (int nf = 0; nf < 4; ++nf) {
    int row = wc * 64 + nf * 16 + l15;
    boff[nf] = 32768 + row * 64 + ((l4 ^ ((row >> 1) & 3)) * 16);
  }

  f32x4 acc[8][4];
  f32x4 zero = {0.f, 0.f, 0.f, 0.f};
#pragma unroll
  for (int mf = 0; mf < 8; ++mf)
#pragma unroll
    for (int nf = 0; nf < 4; ++nf) acc[mf][nf] = zero;
  bf16x8 av[4], bv[4];

  // prologue: buf0 <- t0 {A0,A1,B0,B1}; buf1 <- t1 {B0,A0,B1}
  stA(0, 0, 0); stA(0, 1, 32); stB(0, 0, 0); stB(0, 1, 32);
  stB(1, 0, 64); stA(1, 0, 64); stB(1, 1, 96);
  SCHED();
  asm volatile("s_waitcnt vmcnt(6)" ::: "memory");
  BARRIER(); SCHED();

  char* b0 = smem;
  char* b1m = smem + 65536;
  for (int it = 0; it < 11; ++it) {
    const int t1k = (2 * it + 1) * 64;
    int k2i = 2 * it + 2; if (k2i >= 22) k2i -= 22;
    int k3i = 2 * it + 3; if (k3i >= 22) k3i -= 22;
    const int k2 = k2i * 64, k3 = k3i * 64;
    // ph1: buf0 (s0,h0); stage A1(buf1,t1)
    PH2(b0, 0, 0, { stA(1, 1, t1k + 32); }, 99);
    // ph2: buf0 (s0,h1); stage B0(buf0,t0+2)
    PH2(b0, 0, 1, { stB(0, 0, k2); }, 99);
    // ph3: buf0 (s1,h0); stage A0(buf0,t0+2)
    PH2(b0, 1, 0, { stA(0, 0, k2); }, 99);
    // ph4: buf0 (s1,h1); stage B1(buf0,t0+2); vmcnt(6)
    PH2(b0, 1, 1, { stB(0, 1, k2 + 32); }, 6);
    // ph5: buf1 (s0,h0); stage A1(buf0,t0+2)
    PH2(b1m, 0, 0, { stA(0, 1, k2 + 32); }, 99);
    // ph6: buf1 (s0,h1); stage B0(buf1,t1+2)
    PH2(b1m, 0, 1, { stB(1, 0, k3); }, 99);
    // ph7: buf1 (s1,h0); stage A0(buf1,t1+2)
    PH2(b1m, 1, 0, { stA(1, 0, k3); }, 99);
    // ph8: buf1 (s1,h1); stage B1(buf1,t1+2); vmcnt(6)
    PH2(b1m, 1, 1, { stB(1, 1, k3 + 32); }, 6);
  }
  asm volatile("s_waitcnt vmcnt(0)" ::: "memory");

#pragma unroll
  for (int mf = 0; mf < 8; ++mf)
#pragma unroll
    for (int r = 0; r < 4; ++r) {
      int idx = row0 + wr * 128 + mf * 16 + l4 * 4 + r;
      if (ATOMIC) {
        float p = bp[e * N_TOK + idx];
        int tok = btok[e * N_TOK + idx] & (N_TOK - 1);
#pragma unroll
        for (int nf = 0; nf < 4; ++nf) {
          int col = c0 + wc * 64 + nf * 16 + l15;
          atomicAdd(&y[(size_t)tok * C_DIM + col], p * acc[mf][nf][r]);
        }
      } else {
#pragma unroll
        for (int nf = 0; nf < 4; ++nf) {
          int col = c0 + wc * 64 + nf * 16 + l15;
          y[(size_t)idx * C_DIM + col] = acc[mf][nf][r];
        }
      }
    }
}

extern "C" void kernel_launch(void* const* d_in, const int* in_sizes, int n_in,
                              void* d_out, int out_size, void* d_ws, size_t ws_size,
                              hipStream_t stream) {
  const float* x = (const float*)d_in[0];
  const float* Wg = (const float*)d_in[1];
  const float* W1 = (const float*)d_in[2];
  const float* W2 = (const float*)d_in[3];
  const float* W3 = (const float*)d_in[4];
  const float* Ws1 = (const float*)d_in[5];
  const float* Ws2 = (const float*)d_in[6];
  const float* Ws3 = (const float*)d_in[7];
  float* y = (float*)d_out;
  char* ws = (char*)d_ws;

  int* cnt = (int*)(ws + CNT_OFF);
  int* offs = (int*)(ws + OFFS_OFF);
  int* btok = (int*)(ws + BTOK_OFF);
  float* bp = (float*)(ws + BP_OFF);
  bf16* xb = (bf16*)(ws + XB_OFF);
  bf16* wb1 = (bf16*)(ws + WB1_OFF);
  bf16* wb2 = (bf16*)(ws + WB2_OFF);
  bf16* wb3 = (bf16*)(ws + WB3_OFF);
  bf16* H = (bf16*)(ws + H_OFF);

  hipMemsetAsync(ws, 0, ROUTER_END, stream);

  auto conv = [&](const float* s, bf16* d, size_t n) {
    int n8 = (int)(n / 8);
    convert_kernel<<<(n8 + 255) / 256, 256, 0, stream>>>(s, d, n8);
  };
  conv(x, xb, (size_t)N_TOK * C_DIM);
  conv(W1, wb1, (size_t)NE * I_DIM * C_DIM);
  conv(Ws1, wb1 + (size_t)NE * I_DIM * C_DIM, (size_t)I_DIM * C_DIM);
  conv(W2, wb2, (size_t)NE * I_DIM * C_DIM);
  conv(Ws2, wb2 + (size_t)NE * I_DIM * C_DIM, (size_t)I_DIM * C_DIM);
  conv(W3, wb3, (size_t)NE * C_DIM * I_DIM);
  conv(Ws3, wb3 + (size_t)NE * C_DIM * I_DIM, (size_t)C_DIM * I_DIM);

  router_kernel<<<N_TOK / 4, 256, 0, stream>>>(x, Wg, cnt, btok, bp);
  offsets_kernel<<<1, 64, 0, stream>>>(cnt, offs);

  stage1_kernel<<<dim3(32, 11, NEA), 512, 0, stream>>>(xb, wb1, wb2, cnt, offs, btok, H);
  stage2_kernel<0><<<dim3(32, 4, 1), 512, 0, stream>>>(H, wb3, cnt, offs, btok, bp, y);
  stage2_kernel<1><<<dim3(32, 4, NE), 512, 0, stream>>>(H, wb3, cnt, offs, btok, bp, y);
}

// Round 3
// 671.715 us; speedup vs baseline: 1.4437x; 1.4437x over previous
//
#include <hip/hip_runtime.h>
#include <stdint.h>

typedef __bf16 bf16;
typedef __attribute__((ext_vector_type(8))) __bf16 bf16x8;
typedef __attribute__((ext_vector_type(4))) float f32x4;

#define N_TOK 8192
#define C_DIM 1024
#define I_DIM 1408
#define NE 8      // routed experts
#define NEA 9     // + shared expert as slot 8

// ---- workspace byte offsets ----
#define CNT_OFF   0
#define OFFS_OFF  64
#define BTOK_OFF  128
#define BP_OFF    (BTOK_OFF + NE * N_TOK * 4)
#define ROUTER_END (BP_OFF + NE * N_TOK * 4)
#define XB_OFF    (1u << 20)
#define WB1_OFF   (18u << 20)
#define WB2_OFF   (43u << 20)
#define WB3_OFF   (68u << 20)
#define H_OFF     (93u << 20)

__device__ __forceinline__ void gload16(const void* g, void* l) {
  __builtin_amdgcn_global_load_lds(
      (const __attribute__((address_space(1))) void*)g,
      (__attribute__((address_space(3))) void*)l, 16, 0, 0);
}

// ---------------- conversion fp32 -> bf16, 8 elems/thread ----------------
__global__ __launch_bounds__(256) void convert_kernel(
    const float* __restrict__ src, bf16* __restrict__ dst, int n8) {
  int i = blockIdx.x * 256 + threadIdx.x;
  if (i >= n8) return;
  const float* s = src + (size_t)i * 8;
  float4 a = *(const float4*)(s);
  float4 b = *(const float4*)(s + 4);
  bf16x8 v;
  v[0] = (bf16)a.x; v[1] = (bf16)a.y; v[2] = (bf16)a.z; v[3] = (bf16)a.w;
  v[4] = (bf16)b.x; v[5] = (bf16)b.y; v[6] = (bf16)b.z; v[7] = (bf16)b.w;
  *(bf16x8*)(dst + (size_t)i * 8) = v;
}

// ---------------- router: wave per token ----------------
__global__ __launch_bounds__(256) void router_kernel(
    const float* __restrict__ x, const float* __restrict__ Wg,
    int* __restrict__ cnt, int* __restrict__ btok, float* __restrict__ bp) {
  __shared__ __align__(16) float wg[NE * C_DIM];
  int t = threadIdx.x;
#pragma unroll
  for (int j = 0; j < 8; ++j) {
    int idx = (t + 256 * j) * 4;
    *(float4*)&wg[idx] = *(const float4*)&Wg[idx];
  }
  __syncthreads();
  int wid = t >> 6, lane = t & 63;
  int tok = blockIdx.x * 4 + wid;
  const float* xr = x + (size_t)tok * C_DIM;
  float acc[NE];
#pragma unroll
  for (int e = 0; e < NE; ++e) acc[e] = 0.f;
#pragma unroll
  for (int j = 0; j < 4; ++j) {
    int c4 = (lane + 64 * j) * 4;
    float4 xv = *(const float4*)&xr[c4];
#pragma unroll
    for (int e = 0; e < NE; ++e) {
      float4 wv = *(const float4*)&wg[e * C_DIM + c4];
      acc[e] += xv.x * wv.x + xv.y * wv.y + xv.z * wv.z + xv.w * wv.w;
    }
  }
  for (int o = 32; o >= 1; o >>= 1)
#pragma unroll
    for (int e = 0; e < NE; ++e) acc[e] += __shfl_xor(acc[e], o, 64);
  if (lane == 0) {
    float m = acc[0];
#pragma unroll
    for (int e = 1; e < NE; ++e) m = fmaxf(m, acc[e]);
    float p[NE], s = 0.f;
#pragma unroll
    for (int e = 0; e < NE; ++e) { p[e] = __expf(acc[e] - m); s += p[e]; }
    float inv = 1.f / s;
#pragma unroll
    for (int e = 0; e < NE; ++e) p[e] *= inv;
    int e0 = 0; float p0 = p[0];
#pragma unroll
    for (int e = 1; e < NE; ++e) if (p[e] > p0) { p0 = p[e]; e0 = e; }
    int e1 = -1; float p1 = -1.f;
#pragma unroll
    for (int e = 0; e < NE; ++e) {
      if (e == e0) continue;
      if (p[e] > p1) { p1 = p[e]; e1 = e; }
    }
    int pos0 = atomicAdd(&cnt[e0], 1);
    btok[e0 * N_TOK + pos0] = tok; bp[e0 * N_TOK + pos0] = p0;
    int pos1 = atomicAdd(&cnt[e1], 1);
    btok[e1 * N_TOK + pos1] = tok; bp[e1 * N_TOK + pos1] = p1;
  }
}

__global__ void offsets_kernel(const int* __restrict__ cnt, int* __restrict__ offs) {
  if (threadIdx.x == 0) {
    int a = 0;
    for (int e = 0; e < NE; ++e) { offs[e] = a; a += (cnt[e] + 127) & ~127; }
    offs[NE] = a;
  }
}

// swizzled ds_read byte offset for (row, kgroup) in a [128][32] bf16 tile
__device__ __forceinline__ int swz_off(int row, int kg) {
  return row * 64 + ((kg ^ ((row >> 1) & 3)) * 16);
}

// ---------------- stage1: H = silu(X W1^T) * (X W2^T), per expert ----------------
// 3-buffer depth-2 pipeline, counted vmcnt(3) (retires tile t+1 staged a full
// iteration earlier), single raw s_barrier per K-step.
__global__ __launch_bounds__(512) void stage1_kernel(
    const bf16* __restrict__ xb, const bf16* __restrict__ wb1,
    const bf16* __restrict__ wb2, const int* __restrict__ cnt,
    const int* __restrict__ offs, const int* __restrict__ btok,
    bf16* __restrict__ H) {
  int e = blockIdx.z;
  int row0 = blockIdx.x * 128;
  int padded = (e == NE) ? N_TOK : ((cnt[e] + 127) & ~127);
  if (row0 >= padded) return;
  int i0 = blockIdx.y * 128;
  int slotbase = (e == NE) ? 0 : (N_TOK + offs[e]);

  __shared__ __align__(16) char smem[73728];  // 3 x (A 8K | B1 8K | B2 8K)
  int t = threadIdx.x;
  int lane = t & 63, wid = t >> 6;
  int wr = wid >> 2, wc = wid & 3;

  int srow = t >> 2;
  int gsrc = (t & 3) ^ ((srow >> 1) & 3);  // inverse-swizzled source segment
  int aidx = row0 + srow;
  int atok = (e == NE) ? aidx : btok[e * N_TOK + aidx];
  const bf16* aptr = xb + (size_t)atok * C_DIM + gsrc * 8;
  const bf16* b1p = wb1 + ((size_t)e * I_DIM + i0 + srow) * C_DIM + gsrc * 8;
  const bf16* b2p = wb2 + ((size_t)e * I_DIM + i0 + srow) * C_DIM + gsrc * 8;

  f32x4 accG[4][2], accU[4][2];
  f32x4 zero = {0.f, 0.f, 0.f, 0.f};
#pragma unroll
  for (int mf = 0; mf < 4; ++mf)
#pragma unroll
    for (int nf = 0; nf < 2; ++nf) { accG[mf][nf] = zero; accU[mf][nf] = zero; }

  int l15 = lane & 15, kg = lane >> 4;
  int aoff[4], boff[2];
#pragma unroll
  for (int mf = 0; mf < 4; ++mf) aoff[mf] = swz_off(wr * 64 + mf * 16 + l15, kg);
#pragma unroll
  for (int nf = 0; nf < 2; ++nf) boff[nf] = swz_off(wc * 32 + nf * 16 + l15, kg);

  auto stage = [&](int b, int k0) {
    char* base = smem + b * 24576;
    gload16(aptr + k0, base + t * 16);
    gload16(b1p + k0, base + 8192 + t * 16);
    gload16(b2p + k0, base + 16384 + t * 16);
  };

  stage(0, 0);
  stage(1, 32);
  asm volatile("s_waitcnt vmcnt(3)" ::: "memory");
  __builtin_amdgcn_s_barrier();

  int bi0 = 0, bi1 = 1, bi2 = 2;
  for (int kt = 0; kt < 32; ++kt) {
    if (kt < 30) stage(bi2, (kt + 2) * 32);
    char* base = smem + bi0 * 24576;
    bf16x8 a[4], v1[2], v2[2];
#pragma unroll
    for (int mf = 0; mf < 4; ++mf) a[mf] = *(const bf16x8*)(base + aoff[mf]);
#pragma unroll
    for (int nf = 0; nf < 2; ++nf) {
      v1[nf] = *(const bf16x8*)(base + 8192 + boff[nf]);
      v2[nf] = *(const bf16x8*)(base + 16384 + boff[nf]);
    }
#pragma unroll
    for (int mf = 0; mf < 4; ++mf)
#pragma unroll
      for (int nf = 0; nf < 2; ++nf) {
        accG[mf][nf] = __builtin_amdgcn_mfma_f32_16x16x32_bf16(a[mf], v1[nf], accG[mf][nf], 0, 0, 0);
        accU[mf][nf] = __builtin_amdgcn_mfma_f32_16x16x32_bf16(a[mf], v2[nf], accU[mf][nf], 0, 0, 0);
      }
    if (kt < 30) asm volatile("s_waitcnt vmcnt(3)" ::: "memory");
    else asm volatile("s_waitcnt vmcnt(0)" ::: "memory");
    __builtin_amdgcn_s_barrier();
    int tmp = bi0; bi0 = bi1; bi1 = bi2; bi2 = tmp;
  }

#pragma unroll
  for (int mf = 0; mf < 4; ++mf)
#pragma unroll
    for (int nf = 0; nf < 2; ++nf)
#pragma unroll
      for (int r = 0; r < 4; ++r) {
        float g = accG[mf][nf][r];
        float u = accU[mf][nf][r];
        float h = (g / (1.f + __expf(-g))) * u;
        int row = row0 + wr * 64 + mf * 16 + (lane >> 4) * 4 + r;
        int col = i0 + wc * 32 + nf * 16 + l15;
        H[(size_t)(slotbase + row) * I_DIM + col] = (bf16)h;
      }
}

// ---------------- stage2: y (+)= p * (H W3^T) ----------------
// Same 3-buffer counted-vmcnt pipeline, vmcnt(2), 44 K-steps.
template <int ATOMIC>
__global__ __launch_bounds__(512) void stage2_kernel(
    const bf16* __restrict__ H, const bf16* __restrict__ wb3,
    const int* __restrict__ cnt, const int* __restrict__ offs,
    const int* __restrict__ btok, const float* __restrict__ bp,
    float* __restrict__ y) {
  int e = ATOMIC ? blockIdx.z : NE;
  int row0 = blockIdx.x * 128;
  int padded = ATOMIC ? ((cnt[e] + 127) & ~127) : N_TOK;
  if (row0 >= padded) return;
  int c0 = blockIdx.y * 128;
  int slotbase = ATOMIC ? (N_TOK + offs[e]) : 0;

  __shared__ __align__(16) char smem[49152];  // 3 x (A 8K | B 8K)
  int t = threadIdx.x;
  int lane = t & 63, wid = t >> 6;
  int wr = wid >> 2, wc = wid & 3;

  int srow = t >> 2;
  int gsrc = (t & 3) ^ ((srow >> 1) & 3);
  const bf16* aptr = H + (size_t)(slotbase + row0 + srow) * I_DIM + gsrc * 8;
  const bf16* b3p = wb3 + ((size_t)e * C_DIM + c0 + srow) * I_DIM + gsrc * 8;

  f32x4 acc[4][2];
  f32x4 zero = {0.f, 0.f, 0.f, 0.f};
#pragma unroll
  for (int mf = 0; mf < 4; ++mf)
#pragma unroll
    for (int nf = 0; nf < 2; ++nf) acc[mf][nf] = zero;

  int l15 = lane & 15, kg = lane >> 4;
  int aoff[4], boff[2];
#pragma unroll
  for (int mf = 0; mf < 4; ++mf) aoff[mf] = swz_off(wr * 64 + mf * 16 + l15, kg);
#pragma unroll
  for (int nf = 0; nf < 2; ++nf) boff[nf] = swz_off(wc * 32 + nf * 16 + l15, kg);

  auto stage = [&](int b, int k0) {
    char* base = smem + b * 16384;
    gload16(aptr + k0, base + t * 16);
    gload16(b3p + k0, base + 8192 + t * 16);
  };

  stage(0, 0);
  stage(1, 32);
  asm volatile("s_waitcnt vmcnt(2)" ::: "memory");
  __builtin_amdgcn_s_barrier();

  int bi0 = 0, bi1 = 1, bi2 = 2;
  for (int kt = 0; kt < 44; ++kt) {
    if (kt < 42) stage(bi2, (kt + 2) * 32);
    char* base = smem + bi0 * 16384;
    bf16x8 a[4], b[2];
#pragma unroll
    for (int mf = 0; mf < 4; ++mf) a[mf] = *(const bf16x8*)(base + aoff[mf]);
#pragma unroll
    for (int nf = 0; nf < 2; ++nf) b[nf] = *(const bf16x8*)(base + 8192 + boff[nf]);
#pragma unroll
    for (int mf = 0; mf < 4; ++mf)
#pragma unroll
      for (int nf = 0; nf < 2; ++nf)
        acc[mf][nf] = __builtin_amdgcn_mfma_f32_16x16x32_bf16(a[mf], b[nf], acc[mf][nf], 0, 0, 0);
    if (kt < 42) asm volatile("s_waitcnt vmcnt(2)" ::: "memory");
    else asm volatile("s_waitcnt vmcnt(0)" ::: "memory");
    __builtin_amdgcn_s_barrier();
    int tmp = bi0; bi0 = bi1; bi1 = bi2; bi2 = tmp;
  }

#pragma unroll
  for (int mf = 0; mf < 4; ++mf)
#pragma unroll
    for (int r = 0; r < 4; ++r) {
      int idx = row0 + wr * 64 + mf * 16 + (lane >> 4) * 4 + r;
#pragma unroll
      for (int nf = 0; nf < 2; ++nf) {
        float o = acc[mf][nf][r];
        int col = c0 + wc * 32 + nf * 16 + l15;
        if (ATOMIC) {
          float p = bp[e * N_TOK + idx];
          int tok = btok[e * N_TOK + idx];
          atomicAdd(&y[(size_t)tok * C_DIM + col], p * o);
        } else {
          y[(size_t)idx * C_DIM + col] = o;
        }
      }
    }
}

extern "C" void kernel_launch(void* const* d_in, const int* in_sizes, int n_in,
                              void* d_out, int out_size, void* d_ws, size_t ws_size,
                              hipStream_t stream) {
  const float* x = (const float*)d_in[0];
  const float* Wg = (const float*)d_in[1];
  const float* W1 = (const float*)d_in[2];
  const float* W2 = (const float*)d_in[3];
  const float* W3 = (const float*)d_in[4];
  const float* Ws1 = (const float*)d_in[5];
  const float* Ws2 = (const float*)d_in[6];
  const float* Ws3 = (const float*)d_in[7];
  float* y = (float*)d_out;
  char* ws = (char*)d_ws;

  int* cnt = (int*)(ws + CNT_OFF);
  int* offs = (int*)(ws + OFFS_OFF);
  int* btok = (int*)(ws + BTOK_OFF);
  float* bp = (float*)(ws + BP_OFF);
  bf16* xb = (bf16*)(ws + XB_OFF);
  bf16* wb1 = (bf16*)(ws + WB1_OFF);
  bf16* wb2 = (bf16*)(ws + WB2_OFF);
  bf16* wb3 = (bf16*)(ws + WB3_OFF);
  bf16* H = (bf16*)(ws + H_OFF);

  hipMemsetAsync(ws, 0, ROUTER_END, stream);

  auto conv = [&](const float* s, bf16* d, size_t n) {
    int n8 = (int)(n / 8);
    convert_kernel<<<(n8 + 255) / 256, 256, 0, stream>>>(s, d, n8);
  };
  conv(x, xb, (size_t)N_TOK * C_DIM);
  conv(W1, wb1, (size_t)NE * I_DIM * C_DIM);
  conv(Ws1, wb1 + (size_t)NE * I_DIM * C_DIM, (size_t)I_DIM * C_DIM);
  conv(W2, wb2, (size_t)NE * I_DIM * C_DIM);
  conv(Ws2, wb2 + (size_t)NE * I_DIM * C_DIM, (size_t)I_DIM * C_DIM);
  conv(W3, wb3, (size_t)NE * C_DIM * I_DIM);
  conv(Ws3, wb3 + (size_t)NE * C_DIM * I_DIM, (size_t)C_DIM * I_DIM);

  router_kernel<<<N_TOK / 4, 256, 0, stream>>>(x, Wg, cnt, btok, bp);
  offsets_kernel<<<1, 64, 0, stream>>>(cnt, offs);

  stage1_kernel<<<dim3(64, 11, NEA), 512, 0, stream>>>(xb, wb1, wb2, cnt, offs, btok, H);
  stage2_kernel<0><<<dim3(64, 8, 1), 512, 0, stream>>>(H, wb3, cnt, offs, btok, bp, y);
  stage2_kernel<1><<<dim3(64, 8, NE), 512, 0, stream>>>(H, wb3, cnt, offs, btok, bp, y);
}